// Round 8
// baseline (95.803 us; speedup 1.0000x reference)
//
#include <hip/hip_runtime.h>
#include <hip/hip_fp16.h>

// 21-qubit QNN, 3 layers, fused into TWO sweeps via light-cone gate scheduling.
// y bit b <-> qubit 20-b. Sweep A: local window y[0:12] (qubits 8..20), 35 Rots;
// CNOTs folded into LDS-exchange gathers. Sweep B: local window z[0:12]
// (qubits 0..12), 28 Rots; 3 leftover CNOTs folded into block-address perm;
// final-layer CNOTs acting only inside the window are sum-invariant -> skipped.
// z layout: z[0:4]=y[8:12] (asc), z[5:12]=y[13:20], z[13:20]=y[0:7]
// LDS: fp16 double-buffer, ONE barrier per phase (write buf; bar; read buf;
// next phase uses other buf -- WAR-safe because every thread's read of buf P
// precedes the barrier that gates the next write of P).

union H4 { int4 i4; __half2 h[4]; };

__device__ __forceinline__ unsigned SWZ(unsigned i) {
    return i ^ ((i >> 4) & 0xFu) ^ ((i >> 8) & 0xFu);   // bank spread, bijective
}
// CNOT fold groups (ctrl bit = tgt bit + 1 in local space): x ^ ((x>>1) & tgtMask).
// f2: mA = LATER-in-time group (applied first in gather), mB = earlier group.
__device__ __forceinline__ unsigned f1(unsigned x, unsigned m) {
    return x ^ ((x >> 1) & m);
}
__device__ __forceinline__ unsigned f2(unsigned x, unsigned mA, unsigned mB) {
    unsigned t = x ^ ((x >> 1) & mA);
    return t ^ ((t >> 1) & mB);
}

__device__ __forceinline__ void crot(const float2 u00, const float2 u01,
                                     const float2 u10, const float2 u11,
                                     float2& a, float2& b) {
    float2 na, nb;
    na.x = u00.x*a.x - u00.y*a.y + u01.x*b.x - u01.y*b.y;
    na.y = u00.x*a.y + u00.y*a.x + u01.x*b.y + u01.y*b.x;
    nb.x = u10.x*a.x - u10.y*a.y + u11.x*b.x - u11.y*b.y;
    nb.y = u10.x*a.y + u10.y*a.x + u11.x*b.y + u11.y*b.x;
    a = na; b = nb;
}

// apply up to 4 Rots; ids = 21*layer+qubit into gU; id k acts on reg-bit k.
__device__ __forceinline__ void apply4(float2 v[16], const float2* gU,
                                       int id0, int id1, int id2, int id3) {
    const int ids[4] = {id0, id1, id2, id3};
#pragma unroll
    for (int kk = 0; kk < 4; ++kk) {
        const int id = ids[kk];
        if (id < 0) continue;
        const float2 u00 = gU[4*id+0], u01 = gU[4*id+1];
        const float2 u10 = gU[4*id+2], u11 = gU[4*id+3];
#pragma unroll
        for (int x = 0; x < 16; ++x)
            if (!(x & (1 << kk)))
                crot(u00, u01, u10, u11, v[x], v[x | (1 << kk)]);
    }
}

__device__ __forceinline__ void prep_gates_lds(const float* __restrict__ param,
                                               float2* gU, unsigned tid) {
    if (tid < 63) {
        float phi = param[3*tid+0], th = param[3*tid+1], om = param[3*tid+2];
        float s, c;   __sincosf(0.5f*th, &s, &c);
        float sp, cp; __sincosf(-0.5f*(phi+om), &sp, &cp);
        float sm, cm; __sincosf( 0.5f*(phi-om), &sm, &cm);
        gU[4*tid+0] = make_float2( cp*c,  sp*c);
        gU[4*tid+1] = make_float2(-cm*s, -sm*s);
        gU[4*tid+2] = make_float2( cm*s, -sm*s);
        gU[4*tid+3] = make_float2( cp*c, -sp*c);
    }
}

// ---- phase index mappings: (tid 9b, reg 4b) -> 13-bit local index e ----
// sweep A (e = y bits 0..12)
__device__ __forceinline__ unsigned E1A (unsigned t, unsigned r){ return (t<<4)|r; }                                   // regs e{0..3}
__device__ __forceinline__ unsigned E2A (unsigned t, unsigned r){ return ((t>>4)<<8)|(r<<4)|(t&15u); }                 // regs e{4..7}
__device__ __forceinline__ unsigned E3A (unsigned t, unsigned r){ return ((t>>8)<<12)|(r<<8)|(t&255u); }               // regs e{8..11}
__device__ __forceinline__ unsigned E4A (unsigned t, unsigned r){                                                      // regs e{7,8,9,12}
    return (t&127u) | (((t>>7)&3u)<<10) | ((r&1u)<<7) | (((r>>1)&1u)<<8) | (((r>>2)&1u)<<9) | (((r>>3)&1u)<<12);
}
__device__ __forceinline__ unsigned E5A (unsigned t, unsigned r){                                                      // regs e{5,6,10,11}
    return (t&31u) | (((t>>5)&7u)<<7) | (((t>>8)&1u)<<12) | ((r&1u)<<5) | (((r>>1)&1u)<<6) | (((r>>2)&1u)<<10) | (((r>>3)&1u)<<11);
}
__device__ __forceinline__ unsigned E6A (unsigned t, unsigned r){ return (t&1u) | (((t>>1)&255u)<<5) | (r<<1); }       // regs e{1..4}
__device__ __forceinline__ unsigned E7A (unsigned t, unsigned r){                                                      // regs e{0,7,8,9}
    return ((t&63u)<<1) | (((t>>6)&7u)<<10) | (r&1u) | (((r>>1)&1u)<<7) | (((r>>2)&1u)<<8) | (((r>>3)&1u)<<9);
}
__device__ __forceinline__ unsigned E8A (unsigned t, unsigned r){ return (t&7u) | (((t>>3)&63u)<<7) | ((r&15u)<<3); }  // regs e{3..6}
__device__ __forceinline__ unsigned E9A (unsigned t, unsigned r){ return (t<<4)|r; }                                   // regs e{0..3}
// sweep B (e = z bits 0..12)
__device__ __forceinline__ unsigned E1B (unsigned t, unsigned r){ return (t&511u) | (r<<9); }                          // regs e{9..12}
__device__ __forceinline__ unsigned E2B (unsigned t, unsigned r){ return (t&31u) | (((t>>5)&15u)<<9) | (r<<5); }       // regs e{5..8}
__device__ __forceinline__ unsigned E5B (unsigned t, unsigned r){                                                      // regs e{4,10,11,12}
    return (t&15u) | (((t>>4)&31u)<<5) | ((r&1u)<<4) | (((r>>1)&1u)<<10) | (((r>>2)&1u)<<11) | (((r>>3)&1u)<<12);
}
__device__ __forceinline__ unsigned E6B (unsigned t, unsigned r){ return (t&63u) | (((t>>6)&7u)<<10) | (r<<6); }       // regs e{6..9}
__device__ __forceinline__ unsigned E7B (unsigned t, unsigned r){ return (t&3u) | (((t>>2)&127u)<<6) | (r<<2); }       // regs e{2..5}

// one phase: write current mapping to BUF (fp16), barrier, read next mapping
#define PHASE(BUF, EW, ER) do { \
    _Pragma("unroll") for (int r = 0; r < 16; ++r) { unsigned e_ = (EW); BUF[SWZ(e_)] = __float22half2_rn(v[r]); } \
    __syncthreads(); \
    _Pragma("unroll") for (int r = 0; r < 16; ++r) { unsigned e_ = (ER); v[r] = __half22float2(BUF[SWZ(e_)]); } \
    } while (0)

__global__ __launch_bounds__(512, 4) void sweepA(const float* __restrict__ feat,
                                                 const float* __restrict__ param,
                                                 __half2* __restrict__ zbuf,
                                                 float* __restrict__ out) {
    __shared__ __half2 sh0[8192];
    __shared__ __half2 sh1[8192];
    __shared__ float2 gU[252];
    const unsigned tid = threadIdx.x;
    const unsigned F = blockIdx.x;                 // y bits 13..20
    if (F == 0 && tid == 0) out[0] = 0.0f;
    prep_gates_lds(param, gU, tid);

    float2 v[16];
    {   // load: regs = y{0..3}, 16 consecutive fp32 feats per thread
        const float4* fp = (const float4*)(feat + (((size_t)F) << 13) + (tid << 4));
#pragma unroll
        for (int c = 0; c < 4; ++c) {
            float4 f = fp[c];
            v[4*c+0] = make_float2(f.x, 0.f); v[4*c+1] = make_float2(f.y, 0.f);
            v[4*c+2] = make_float2(f.z, 0.f); v[4*c+3] = make_float2(f.w, 0.f);
        }
    }
    __syncthreads();                                // gU ready
    apply4(v, gU, 20, 19, 18, 17);                  // R0 q20,q19,q18,q17
    PHASE(sh0, E1A(tid,r), E2A(tid,r));
    apply4(v, gU, 16, 15, 14, 13);                  // R0 q16..q13
    PHASE(sh1, E2A(tid,r), E3A(tid,r));
    apply4(v, gU, 12, 11, 10, 9);                   // R0 q12..q9
    // fold: O0{(11,12)..(19,20)} later, E0{(10,11)..(18,19)} earlier
    PHASE(sh0, E3A(tid,r), f2(E4A(tid,r), 0x155u, 0x2AAu));
    apply4(v, gU, 34, 33, 32, 8);                   // R1 q13,q12,q11 ; R0 q8
    // fold: O0(9,10) later, E0(8,9) earlier
    PHASE(sh1, E4A(tid,r), f2(E5A(tid,r), 0x400u, 0x800u));
    apply4(v, gU, 36, 35, 31, 30);                  // R1 q15,q14,q10,q9
    // fold: O1{(11,12),(13,14)} later, E1{(10,11),(12,13),(14,15)} earlier
    PHASE(sh0, E5A(tid,r), f2(E6A(tid,r), 0x140u, 0x2A0u));
    apply4(v, gU, 40, 39, 38, 37);                  // R1 q19,q18,q17,q16
    // fold: O1{(15,16),(17,18)} later, E1{(16,17),(18,19)} earlier
    PHASE(sh1, E6A(tid,r), f2(E7A(tid,r), 0x014u, 0x00Au));
    apply4(v, gU, 41, 55, 54, 53);                  // R1 q20 ; R2 q13,q12,q11
    // fold: O1(19,20) + E2(12,13)  (disjoint bits)
    PHASE(sh0, E7A(tid,r), f1(E8A(tid,r), 0x081u));
    apply4(v, gU, 59, 58, 57, 56);                  // R2 q17,q16,q15,q14
    // fold: O2{(13,14),(15,16)} later, E2{(14,15),(16,17)} earlier
    PHASE(sh1, E8A(tid,r), f2(E9A(tid,r), 0x050u, 0x028u));
    apply4(v, gU, 62, 61, 60, -1);                  // R2 q20,q19,q18
    // leftover E2(18,19), O2(17,18),(19,20) -> folded into sweepB block perm

    // final: park at E9A layout, then COALESCED store (same z layout as before:
    // z[0:4]=e[8:12], z[5:12]=F, z[13:20]=e[0:7]). Thread tid, chunk j handles
    // int4 index (j<<9)|tid -> 8 consecutive lanes fill one full 128B line.
#pragma unroll
    for (int r = 0; r < 16; ++r) sh0[SWZ(E9A(tid,(unsigned)r))] = __float22half2_rn(v[r]);
    __syncthreads();
    {
        int4* zb4 = (int4*)zbuf;
#pragma unroll
        for (unsigned j = 0; j < 4; ++j) {
            const unsigned chunk = (j << 6) | (tid >> 3);        // e[0:7]
            const unsigned ebase = chunk | ((tid & 7u) << 10);   // e[10:12]=tid&7
            H4 y;
#pragma unroll
            for (unsigned k = 0; k < 4; ++k)
                y.h[k] = sh0[SWZ(ebase | ((k & 1u) << 8) | ((k >> 1) << 9))];
            zb4[(chunk << 11) | (F << 3) | (tid & 7u)] = y.i4;
        }
    }
}

__global__ __launch_bounds__(512, 4) void sweepB(const __half2* __restrict__ zbuf,
                                                 const float* __restrict__ param,
                                                 float* __restrict__ out) {
    __shared__ __half2 sh0[8192];
    __shared__ __half2 sh1[8192];
    __shared__ float2 gU[252];
    __shared__ float wsum[8];
    const unsigned tid = threadIdx.x;
    const unsigned B = blockIdx.x * 2u;            // z bits 13..20 = y[0:7]; y0=0 only
    prep_gates_lds(param, gU, tid);

    // sweepA-leftover fold on block bits: O2{y1->y0, y3->y2} later, E2{y2->y1} earlier
    unsigned t0 = B ^ ((B >> 1) & 5u);
    const unsigned Bp = t0 ^ ((t0 >> 1) & 2u);
    const int4* src = (const int4*)(zbuf + (((size_t)Bp) << 13));
#pragma unroll
    for (unsigned c = 0; c < 4; ++c) {
        H4 x; x.i4 = src[c * 512 + tid];
        unsigned e = (c << 11) | (tid << 2);
#pragma unroll
        for (unsigned k = 0; k < 4; ++k) sh0[SWZ(e | k)] = x.h[k];
    }
    __syncthreads();

    float2 v[16];
#pragma unroll
    for (int r = 0; r < 16; ++r) v[r] = __half22float2(sh0[SWZ(E1B(tid,(unsigned)r))]);
    apply4(v, gU, 3, 2, 1, 0);                      // R0 q3,q2,q1,q0
    // fold: E0{(0,1),(2,3)} -> tgt e-bits {11,9}
    PHASE(sh1, E1B(tid,r), f1(E2B(tid,r), 0xA00u));
    apply4(v, gU, 7, 6, 5, 4);                      // R0 q7..q4
    // fold: O0{(1,2),(3,4),(5,6),(7,8)} later, E0{(4,5),(6,7)} earlier
    PHASE(sh0, E2B(tid,r), f2(E1B(tid,r), 0x550u, 0x0A0u));
    apply4(v, gU, 24, 23, 22, 21);                  // R1 q3..q0
    // fold: E1{(0,1),(2,3)}
    PHASE(sh1, E1B(tid,r), f1(E2B(tid,r), 0xA00u));
    apply4(v, gU, 28, 27, 26, 25);                  // R1 q7..q4
    // fold: O1{(1,2),(3,4),(5,6)} later, E1{(4,5),(6,7)} earlier
    PHASE(sh0, E2B(tid,r), f2(E5B(tid,r), 0x540u, 0x0A0u));
    apply4(v, gU, 29, 44, 43, 42);                  // R1 q8 ; R2 q2,q1,q0
    // fold: O1{(7,8),(9,10)} later, E1(8,9) earlier
    PHASE(sh1, E5B(tid,r), f2(E6B(tid,r), 0x014u, 0x008u));
    apply4(v, gU, 48, 47, 46, 45);                  // R2 q6,q5,q4,q3
    PHASE(sh0, E6B(tid,r), E7B(tid,r));             // no fold
    apply4(v, gU, 52, 51, 50, 49);                  // R2 q10,q9,q8,q7
    // final E2/O2 inside window: local perms not touching y0 -> sum-invariant, skip
    float acc = 0.f;
#pragma unroll
    for (int r = 0; r < 16; ++r) acc += v[r].x*v[r].x + v[r].y*v[r].y;
    for (int off = 32; off; off >>= 1) acc += __shfl_down(acc, off);
    if ((tid & 63u) == 0) wsum[tid >> 6] = acc;
    __syncthreads();
    if (tid == 0) {
        float s = 0.f;
#pragma unroll
        for (int w = 0; w < 8; ++w) s += wsum[w];
        atomicAdd(out, s);
    }
}

extern "C" void kernel_launch(void* const* d_in, const int* in_sizes, int n_in,
                              void* d_out, int out_size, void* d_ws, size_t ws_size,
                              hipStream_t stream) {
    const float* feat  = (const float*)d_in[0];
    const float* param = (const float*)d_in[1];
    float* out = (float*)d_out;
    __half2* zbuf = (__half2*)d_ws;                // 2^21 * 4B = 8 MB

    sweepA<<<256, 512, 0, stream>>>(feat, param, zbuf, out);
    sweepB<<<128, 512, 0, stream>>>(zbuf, param, out);
}

// Round 9
// 54.410 us; speedup vs baseline: 1.7608x; 1.7608x over previous
//
#include <hip/hip_runtime.h>
#include <hip/hip_fp16.h>

// 21-qubit QNN, 3 layers, fused into TWO sweeps via light-cone gate scheduling.
// y bit b <-> qubit 20-b. Sweep A: local window y[0:12] (qubits 8..20), 35 Rots;
// CNOTs folded into LDS-exchange gathers. Sweep B: local window z[0:12]
// (qubits 0..12), 28 Rots; 3 leftover CNOTs folded into block-address perm;
// final-layer CNOTs acting only inside the window are sum-invariant -> skipped.
// z layout: z[0:4]=y[8:12] (asc), z[5:12]=y[13:20], z[13:20]=y[0:7]
// LDS: float2 DOUBLE-buffer (130 KB -- free: grid==256==#CUs so 1 block/CU
// either way), ONE barrier per phase: write bufA; bar; read bufA; next phase
// uses bufB. WAR-safe: a buffer's re-write is separated from its last read
// by the intervening phase's barrier.

union H4 { int4 i4; __half2 h[4]; };

__device__ __forceinline__ unsigned SWZ(unsigned i) {
    return i ^ ((i >> 4) & 0xFu) ^ ((i >> 8) & 0xFu);   // bank spread, bijective
}
// CNOT fold groups (ctrl bit = tgt bit + 1 in local space): x ^ ((x>>1) & tgtMask).
// f2: mA = LATER-in-time group (applied first in gather), mB = earlier group.
__device__ __forceinline__ unsigned f1(unsigned x, unsigned m) {
    return x ^ ((x >> 1) & m);
}
__device__ __forceinline__ unsigned f2(unsigned x, unsigned mA, unsigned mB) {
    unsigned t = x ^ ((x >> 1) & mA);
    return t ^ ((t >> 1) & mB);
}

__device__ __forceinline__ void crot(const float2 u00, const float2 u01,
                                     const float2 u10, const float2 u11,
                                     float2& a, float2& b) {
    float2 na, nb;
    na.x = u00.x*a.x - u00.y*a.y + u01.x*b.x - u01.y*b.y;
    na.y = u00.x*a.y + u00.y*a.x + u01.x*b.y + u01.y*b.x;
    nb.x = u10.x*a.x - u10.y*a.y + u11.x*b.x - u11.y*b.y;
    nb.y = u10.x*a.y + u10.y*a.x + u11.x*b.y + u11.y*b.x;
    a = na; b = nb;
}

// apply up to 4 Rots; ids = 21*layer+qubit into gU; id k acts on reg-bit k.
__device__ __forceinline__ void apply4(float2 v[16], const float2* gU,
                                       int id0, int id1, int id2, int id3) {
    const int ids[4] = {id0, id1, id2, id3};
#pragma unroll
    for (int kk = 0; kk < 4; ++kk) {
        const int id = ids[kk];
        if (id < 0) continue;
        const float2 u00 = gU[4*id+0], u01 = gU[4*id+1];
        const float2 u10 = gU[4*id+2], u11 = gU[4*id+3];
#pragma unroll
        for (int x = 0; x < 16; ++x)
            if (!(x & (1 << kk)))
                crot(u00, u01, u10, u11, v[x], v[x | (1 << kk)]);
    }
}

__device__ __forceinline__ void prep_gates_lds(const float* __restrict__ param,
                                               float2* gU, unsigned tid) {
    if (tid < 63) {
        float phi = param[3*tid+0], th = param[3*tid+1], om = param[3*tid+2];
        float s, c;   __sincosf(0.5f*th, &s, &c);
        float sp, cp; __sincosf(-0.5f*(phi+om), &sp, &cp);
        float sm, cm; __sincosf( 0.5f*(phi-om), &sm, &cm);
        gU[4*tid+0] = make_float2( cp*c,  sp*c);
        gU[4*tid+1] = make_float2(-cm*s, -sm*s);
        gU[4*tid+2] = make_float2( cm*s, -sm*s);
        gU[4*tid+3] = make_float2( cp*c, -sp*c);
    }
}

// ---- phase index mappings: (tid 9b, reg 4b) -> 13-bit local index e ----
// sweep A (e = y bits 0..12)
__device__ __forceinline__ unsigned E1A (unsigned t, unsigned r){ return (t<<4)|r; }                                   // regs e{0..3}
__device__ __forceinline__ unsigned E2A (unsigned t, unsigned r){ return ((t>>4)<<8)|(r<<4)|(t&15u); }                 // regs e{4..7}
__device__ __forceinline__ unsigned E3A (unsigned t, unsigned r){ return ((t>>8)<<12)|(r<<8)|(t&255u); }               // regs e{8..11}
__device__ __forceinline__ unsigned E4A (unsigned t, unsigned r){                                                      // regs e{7,8,9,12}
    return (t&127u) | (((t>>7)&3u)<<10) | ((r&1u)<<7) | (((r>>1)&1u)<<8) | (((r>>2)&1u)<<9) | (((r>>3)&1u)<<12);
}
__device__ __forceinline__ unsigned E5A (unsigned t, unsigned r){                                                      // regs e{5,6,10,11}
    return (t&31u) | (((t>>5)&7u)<<7) | (((t>>8)&1u)<<12) | ((r&1u)<<5) | (((r>>1)&1u)<<6) | (((r>>2)&1u)<<10) | (((r>>3)&1u)<<11);
}
__device__ __forceinline__ unsigned E6A (unsigned t, unsigned r){ return (t&1u) | (((t>>1)&255u)<<5) | (r<<1); }       // regs e{1..4}
__device__ __forceinline__ unsigned E7A (unsigned t, unsigned r){                                                      // regs e{0,7,8,9}
    return ((t&63u)<<1) | (((t>>6)&7u)<<10) | (r&1u) | (((r>>1)&1u)<<7) | (((r>>2)&1u)<<8) | (((r>>3)&1u)<<9);
}
__device__ __forceinline__ unsigned E8A (unsigned t, unsigned r){ return (t&7u) | (((t>>3)&63u)<<7) | ((r&15u)<<3); }  // regs e{3..6}
__device__ __forceinline__ unsigned E9A (unsigned t, unsigned r){ return (t<<4)|r; }                                   // regs e{0..3}
__device__ __forceinline__ unsigned E10A(unsigned t, unsigned r){                                                      // regs e{8..11}, t8->e12
    return (t&255u) | (((t>>8)&1u)<<12) | ((r&1u)<<8) | (((r>>1)&1u)<<9) | (((r>>2)&1u)<<10) | (((r>>3)&1u)<<11);
}
// sweep B (e = z bits 0..12)
__device__ __forceinline__ unsigned E1B (unsigned t, unsigned r){ return (t&511u) | (r<<9); }                          // regs e{9..12}
__device__ __forceinline__ unsigned E2B (unsigned t, unsigned r){ return (t&31u) | (((t>>5)&15u)<<9) | (r<<5); }       // regs e{5..8}
__device__ __forceinline__ unsigned E5B (unsigned t, unsigned r){                                                      // regs e{4,10,11,12}
    return (t&15u) | (((t>>4)&31u)<<5) | ((r&1u)<<4) | (((r>>1)&1u)<<10) | (((r>>2)&1u)<<11) | (((r>>3)&1u)<<12);
}
__device__ __forceinline__ unsigned E6B (unsigned t, unsigned r){ return (t&63u) | (((t>>6)&7u)<<10) | (r<<6); }       // regs e{6..9}
__device__ __forceinline__ unsigned E7B (unsigned t, unsigned r){ return (t&3u) | (((t>>2)&127u)<<6) | (r<<2); }       // regs e{2..5}

// one phase: write current mapping to BUF, barrier, read next mapping from BUF.
// NO trailing barrier: next phase writes the OTHER buffer.
#define PHASE(BUF, EW, ER) do { \
    _Pragma("unroll") for (int r = 0; r < 16; ++r) { unsigned e_ = (EW); BUF[SWZ(e_)] = v[r]; } \
    __syncthreads(); \
    _Pragma("unroll") for (int r = 0; r < 16; ++r) { unsigned e_ = (ER); v[r] = BUF[SWZ(e_)]; } \
    } while (0)

__global__ __launch_bounds__(512, 2) void sweepA(const float* __restrict__ feat,
                                                 const float* __restrict__ param,
                                                 __half2* __restrict__ zbuf,
                                                 float* __restrict__ out) {
    __shared__ float2 sh0[8192];
    __shared__ float2 sh1[8192];
    __shared__ float2 gU[252];
    const unsigned tid = threadIdx.x;
    const unsigned F = blockIdx.x;                 // y bits 13..20
    if (F == 0 && tid == 0) out[0] = 0.0f;
    prep_gates_lds(param, gU, tid);

    float2 v[16];
    {   // load: regs = y{0..3}, 16 consecutive fp32 feats per thread
        const float4* fp = (const float4*)(feat + (((size_t)F) << 13) + (tid << 4));
#pragma unroll
        for (int c = 0; c < 4; ++c) {
            float4 f = fp[c];
            v[4*c+0] = make_float2(f.x, 0.f); v[4*c+1] = make_float2(f.y, 0.f);
            v[4*c+2] = make_float2(f.z, 0.f); v[4*c+3] = make_float2(f.w, 0.f);
        }
    }
    __syncthreads();                                // gU ready
    apply4(v, gU, 20, 19, 18, 17);                  // R0 q20,q19,q18,q17
    PHASE(sh0, E1A(tid,r), E2A(tid,r));
    apply4(v, gU, 16, 15, 14, 13);                  // R0 q16..q13
    PHASE(sh1, E2A(tid,r), E3A(tid,r));
    apply4(v, gU, 12, 11, 10, 9);                   // R0 q12..q9
    // fold: O0{(11,12)..(19,20)} later, E0{(10,11)..(18,19)} earlier
    PHASE(sh0, E3A(tid,r), f2(E4A(tid,r), 0x155u, 0x2AAu));
    apply4(v, gU, 34, 33, 32, 8);                   // R1 q13,q12,q11 ; R0 q8
    // fold: O0(9,10) later, E0(8,9) earlier
    PHASE(sh1, E4A(tid,r), f2(E5A(tid,r), 0x400u, 0x800u));
    apply4(v, gU, 36, 35, 31, 30);                  // R1 q15,q14,q10,q9
    // fold: O1{(11,12),(13,14)} later, E1{(10,11),(12,13),(14,15)} earlier
    PHASE(sh0, E5A(tid,r), f2(E6A(tid,r), 0x140u, 0x2A0u));
    apply4(v, gU, 40, 39, 38, 37);                  // R1 q19,q18,q17,q16
    // fold: O1{(15,16),(17,18)} later, E1{(16,17),(18,19)} earlier
    PHASE(sh1, E6A(tid,r), f2(E7A(tid,r), 0x014u, 0x00Au));
    apply4(v, gU, 41, 55, 54, 53);                  // R1 q20 ; R2 q13,q12,q11
    // fold: O1(19,20) + E2(12,13)  (disjoint bits)
    PHASE(sh0, E7A(tid,r), f1(E8A(tid,r), 0x081u));
    apply4(v, gU, 59, 58, 57, 56);                  // R2 q17,q16,q15,q14
    // fold: O2{(13,14),(15,16)} later, E2{(14,15),(16,17)} earlier
    PHASE(sh1, E8A(tid,r), f2(E9A(tid,r), 0x050u, 0x028u));
    apply4(v, gU, 62, 61, 60, -1);                  // R2 q20,q19,q18
    // leftover E2(18,19), O2(17,18),(19,20) -> folded into sweepB block perm
    PHASE(sh0, E9A(tid,r), E10A(tid,r));            // re-layout for z-store
    {   // store: z[0:3]=regs(y8..y11), z4=t8(y12), z[5:12]=F, z[13:20]=t[0:7]
        const unsigned zbase = ((tid & 255u) << 13) | (((tid >> 8) & 1u) << 4) | (F << 5);
        int4* zb4 = (int4*)zbuf;
#pragma unroll
        for (int j = 0; j < 4; ++j) {
            H4 y;
            y.h[0] = __float22half2_rn(v[4*j+0]);
            y.h[1] = __float22half2_rn(v[4*j+1]);
            y.h[2] = __float22half2_rn(v[4*j+2]);
            y.h[3] = __float22half2_rn(v[4*j+3]);
            zb4[(zbase >> 2) + j] = y.i4;
        }
    }
}

__global__ __launch_bounds__(512, 2) void sweepB(const __half2* __restrict__ zbuf,
                                                 const float* __restrict__ param,
                                                 float* __restrict__ out) {
    __shared__ float2 sh0[8192];
    __shared__ float2 sh1[8192];
    __shared__ float2 gU[252];
    __shared__ float wsum[8];
    const unsigned tid = threadIdx.x;
    const unsigned B = blockIdx.x * 2u;            // z bits 13..20 = y[0:7]; y0=0 only
    prep_gates_lds(param, gU, tid);

    // sweepA-leftover fold on block bits: O2{y1->y0, y3->y2} later, E2{y2->y1} earlier
    unsigned t0 = B ^ ((B >> 1) & 5u);
    const unsigned Bp = t0 ^ ((t0 >> 1) & 2u);
    const int4* src = (const int4*)(zbuf + (((size_t)Bp) << 13));
#pragma unroll
    for (unsigned c = 0; c < 4; ++c) {
        H4 x; x.i4 = src[c * 512 + tid];
        unsigned e = (c << 11) | (tid << 2);
        sh0[SWZ(e)]     = __half22float2(x.h[0]);
        sh0[SWZ(e | 1)] = __half22float2(x.h[1]);
        sh0[SWZ(e | 2)] = __half22float2(x.h[2]);
        sh0[SWZ(e | 3)] = __half22float2(x.h[3]);
    }
    __syncthreads();                                // gU + tile ready

    float2 v[16];
#pragma unroll
    for (int r = 0; r < 16; ++r) v[r] = sh0[SWZ(E1B(tid,(unsigned)r))];
    apply4(v, gU, 3, 2, 1, 0);                      // R0 q3,q2,q1,q0
    // fold: E0{(0,1),(2,3)} -> tgt e-bits {11,9}
    PHASE(sh1, E1B(tid,r), f1(E2B(tid,r), 0xA00u));
    apply4(v, gU, 7, 6, 5, 4);                      // R0 q7..q4
    // fold: O0{(1,2),(3,4),(5,6),(7,8)} later, E0{(4,5),(6,7)} earlier
    PHASE(sh0, E2B(tid,r), f2(E1B(tid,r), 0x550u, 0x0A0u));
    apply4(v, gU, 24, 23, 22, 21);                  // R1 q3..q0
    // fold: E1{(0,1),(2,3)}
    PHASE(sh1, E1B(tid,r), f1(E2B(tid,r), 0xA00u));
    apply4(v, gU, 28, 27, 26, 25);                  // R1 q7..q4
    // fold: O1{(1,2),(3,4),(5,6)} later, E1{(4,5),(6,7)} earlier
    PHASE(sh0, E2B(tid,r), f2(E5B(tid,r), 0x540u, 0x0A0u));
    apply4(v, gU, 29, 44, 43, 42);                  // R1 q8 ; R2 q2,q1,q0
    // fold: O1{(7,8),(9,10)} later, E1(8,9) earlier
    PHASE(sh1, E5B(tid,r), f2(E6B(tid,r), 0x014u, 0x008u));
    apply4(v, gU, 48, 47, 46, 45);                  // R2 q6,q5,q4,q3
    PHASE(sh0, E6B(tid,r), E7B(tid,r));             // no fold
    apply4(v, gU, 52, 51, 50, 49);                  // R2 q10,q9,q8,q7
    // final E2/O2 inside window: local perms not touching y0 -> sum-invariant, skip
    float acc = 0.f;
#pragma unroll
    for (int r = 0; r < 16; ++r) acc += v[r].x*v[r].x + v[r].y*v[r].y;
    for (int off = 32; off; off >>= 1) acc += __shfl_down(acc, off);
    if ((tid & 63u) == 0) wsum[tid >> 6] = acc;
    __syncthreads();
    if (tid == 0) {
        float s = 0.f;
#pragma unroll
        for (int w = 0; w < 8; ++w) s += wsum[w];
        atomicAdd(out, s);
    }
}

extern "C" void kernel_launch(void* const* d_in, const int* in_sizes, int n_in,
                              void* d_out, int out_size, void* d_ws, size_t ws_size,
                              hipStream_t stream) {
    const float* feat  = (const float*)d_in[0];
    const float* param = (const float*)d_in[1];
    float* out = (float*)d_out;
    __half2* zbuf = (__half2*)d_ws;                // 2^21 * 4B = 8 MB

    sweepA<<<256, 512, 0, stream>>>(feat, param, zbuf, out);
    sweepB<<<128, 512, 0, stream>>>(zbuf, param, out);
}